// Round 5
// baseline (229.588 us; speedup 1.0000x reference)
//
#include <hip/hip_runtime.h>
#include <math.h>

#define DIM 64
#define FDIM 256   // DIM * H (H=4)

// bf16 (stored as ushort) -> float helpers: elem pair packed in a uint
__device__ __forceinline__ float blo(unsigned int u) {
    union { unsigned int i; float f; } x; x.i = u << 16; return x.f;
}
__device__ __forceinline__ float bhi(unsigned int u) {
    union { unsigned int i; float f; } x; x.i = u & 0xffff0000u; return x.f;
}
__device__ __forceinline__ void cvt16(uint4 a, uint4 b, float* f) {
    f[0]=blo(a.x);  f[1]=bhi(a.x);  f[2]=blo(a.y);  f[3]=bhi(a.y);
    f[4]=blo(a.z);  f[5]=bhi(a.z);  f[6]=blo(a.w);  f[7]=bhi(a.w);
    f[8]=blo(b.x);  f[9]=bhi(b.x);  f[10]=blo(b.y); f[11]=bhi(b.y);
    f[12]=blo(b.z); f[13]=bhi(b.z); f[14]=blo(b.w); f[15]=bhi(b.w);
}

// ---------------- Stage 1: ft = bf16(h_v @ W_fc^T + b_fc)  -> [N, 256] ----------------
// Thread t owns output column t; h-row values are wave-uniform (L1/scalar broadcast).
__global__ __launch_bounds__(256) void fc_kernel(const float* __restrict__ h,
                                                 const float* __restrict__ W,
                                                 const float* __restrict__ b,
                                                 unsigned short* __restrict__ ft, int N)
{
    int t = threadIdx.x;              // output column 0..255
    float w[DIM];
#pragma unroll
    for (int j = 0; j < DIM / 4; ++j) {
        float4 v = *(const float4*)(W + (size_t)t * DIM + j * 4);
        w[4 * j + 0] = v.x; w[4 * j + 1] = v.y;
        w[4 * j + 2] = v.z; w[4 * j + 3] = v.w;
    }
    float bt = b[t];
    for (int r = blockIdx.x; r < N; r += gridDim.x) {
        const float4* h4 = (const float4*)(h + (size_t)r * DIM);
        float acc = bt;
#pragma unroll
        for (int j = 0; j < DIM / 4; ++j) {
            float4 hv = h4[j];       // uniform address across the wave
            acc = fmaf(hv.x, w[4 * j + 0], acc);
            acc = fmaf(hv.y, w[4 * j + 1], acc);
            acc = fmaf(hv.z, w[4 * j + 2], acc);
            acc = fmaf(hv.w, w[4 * j + 3], acc);
        }
        union { float f; unsigned int i; } x; x.f = acc;     // RNE to bf16
        unsigned int r16 = (x.i + 0x7fffu + ((x.i >> 16) & 1u)) >> 16;
        ft[(size_t)r * FDIM + t] = (unsigned short)r16;
    }
}

// ---------------- Counting sort of edges by dst ----------------
__global__ void zero_kernel(int* __restrict__ p, int n)
{
    int i = blockIdx.x * blockDim.x + threadIdx.x;
    for (; i < n; i += gridDim.x * blockDim.x) p[i] = 0;
}

__global__ void hist_kernel(const int* __restrict__ dst, int* __restrict__ cnt, int E)
{
    int i = blockIdx.x * blockDim.x + threadIdx.x;
    for (; i < E; i += gridDim.x * blockDim.x) atomicAdd(&cnt[dst[i]], 1);
}

// Multi-block exclusive scan of cnt[0..N) in 3 phases.
__global__ __launch_bounds__(256) void scanA_kernel(const int* __restrict__ cnt,
                                                    int* __restrict__ off,
                                                    int* __restrict__ bsum, int N)
{
    __shared__ int sh[256];
    int t = threadIdx.x;
    int i = blockIdx.x * 256 + t;
    int v = (i < N) ? cnt[i] : 0;
    sh[t] = v;
    __syncthreads();
#pragma unroll
    for (int o = 1; o < 256; o <<= 1) {
        int x = (t >= o) ? sh[t - o] : 0;
        __syncthreads();
        sh[t] += x;
        __syncthreads();
    }
    if (i < N) off[i] = sh[t] - v;          // local exclusive
    if (t == 255) bsum[blockIdx.x] = sh[255];
}

__global__ __launch_bounds__(256) void scanB_kernel(int* __restrict__ bsum, int nb)
{
    __shared__ int sh[256];
    int t = threadIdx.x;
    int carry = 0;
    for (int base = 0; base < nb; base += 256) {
        int i = base + t;
        int v = (i < nb) ? bsum[i] : 0;
        sh[t] = v;
        __syncthreads();
#pragma unroll
        for (int o = 1; o < 256; o <<= 1) {
            int x = (t >= o) ? sh[t - o] : 0;
            __syncthreads();
            sh[t] += x;
            __syncthreads();
        }
        if (i < nb) bsum[i] = carry + sh[t] - v;   // exclusive
        int tot = sh[255];
        __syncthreads();
        carry += tot;
    }
}

__global__ void scanC_kernel(int* __restrict__ off, int* __restrict__ cur,
                             const int* __restrict__ bsum, int N, int E)
{
    int i = blockIdx.x * blockDim.x + threadIdx.x;
    if (i < N) {
        int v = off[i] + bsum[i >> 8];
        off[i] = v;
        cur[i] = v;
    }
    if (i == 0) off[N] = E;
}

__global__ void scatter_kernel(const int* __restrict__ src, const int* __restrict__ dst,
                               int* __restrict__ cur, int* __restrict__ ssrc, int E)
{
    int i = blockIdx.x * blockDim.x + threadIdx.x;
    for (; i < E; i += gridDim.x * blockDim.x) {
        int d = dst[i];
        int pos = atomicAdd(&cur[d], 1);
        ssrc[pos] = src[i];
    }
}

// ---------------- Fused: score + edge-softmax (online) + weighted sum + head-max ----------------
// One wave per destination node, 4 edges per iteration.
// Quarter q (16 lanes) owns edge base+q; lane ql within quarter owns dims 16*ql..16*ql+15.
__global__ __launch_bounds__(256) void agg_kernel(const unsigned short* __restrict__ ft,
                                                  const int* __restrict__ off,
                                                  const int* __restrict__ ssrc,
                                                  const float* __restrict__ Wpi,
                                                  float* __restrict__ out, int N)
{
    int wid = (blockIdx.x * blockDim.x + threadIdx.x) >> 6;
    int lane = threadIdx.x & 63;
    if (wid >= N) return;
    int q  = lane >> 4;
    int ql = lane & 15;

    // fdw[j] = ft[wid][16*ql+j] * Wpi[16*ql+j]
    float fdw[16];
    {
        const unsigned short* drow = ft + (size_t)wid * FDIM + ql * 16;
        uint4 a = *(const uint4*)(drow);
        uint4 b = *(const uint4*)(drow + 8);
        float fd[16];
        cvt16(a, b, fd);
        const float4* wp4 = (const float4*)(Wpi + ql * 16);
#pragma unroll
        for (int j = 0; j < 4; ++j) {
            float4 w = wp4[j];
            fdw[4 * j + 0] = fd[4 * j + 0] * w.x;
            fdw[4 * j + 1] = fd[4 * j + 1] * w.y;
            fdw[4 * j + 2] = fd[4 * j + 2] * w.z;
            fdw[4 * j + 3] = fd[4 * j + 3] * w.w;
        }
    }

    int e0 = off[wid], e1 = off[wid + 1];
    float m = -INFINITY, l = 0.f;
    float acc[16];
#pragma unroll
    for (int j = 0; j < 16; ++j) acc[j] = 0.f;

    for (int base = e0; base < e1; base += 4) {
        int ei = base + q;
        bool valid = ei < e1;
        int idx = valid ? ei : base;            // safe (base < e1 inside loop)
        int sv = ssrc[idx];
        const unsigned short* srow = ft + (size_t)sv * FDIM + ql * 16;
        uint4 a = *(const uint4*)(srow);
        uint4 b = *(const uint4*)(srow + 8);
        float fs[16];
        cvt16(a, b, fs);

        float p = 0.f;
#pragma unroll
        for (int j = 0; j < 16; ++j) p = fmaf(fs[j], fdw[j], p);
        // reduce within quarter (bits 0..3)
        p += __shfl_xor(p, 1, 64);
        p += __shfl_xor(p, 2, 64);
        p += __shfl_xor(p, 4, 64);
        p += __shfl_xor(p, 8, 64);
        float s = p > 0.f ? p : 0.2f * p;       // LeakyReLU(0.2)
        if (!valid) s = -INFINITY;
        // max over the 4 quarters (bits 4,5) -> wave-uniform
        float smax = fmaxf(s, __shfl_xor(s, 16, 64));
        smax = fmaxf(smax, __shfl_xor(smax, 32, 64));
        if (smax > m) {                          // wave-uniform rescale (rare after warmup)
            float sc = __expf(m - smax);         // first iter: exp(-inf)=0
            l *= sc;
#pragma unroll
            for (int j = 0; j < 16; ++j) acc[j] *= sc;
            m = smax;
        }
        float pe = __expf(s - m);                // invalid quarter: exp(-inf)=0
        l += pe;
#pragma unroll
        for (int j = 0; j < 16; ++j) acc[j] = fmaf(pe, fs[j], acc[j]);
    }

    // sum the 4 quarter copies (each quarter-uniform)
#pragma unroll
    for (int j = 0; j < 16; ++j) {
        acc[j] += __shfl_xor(acc[j], 16, 64);
        acc[j] += __shfl_xor(acc[j], 32, 64);
    }
    l += __shfl_xor(l, 16, 64);
    l += __shfl_xor(l, 32, 64);
    float inv = (l > 0.f) ? 1.f / l : 0.f;

    // head-max: dim D = 16*ql+j, head = ql>>2, out-dim = 16*(ql&3)+j
    float r[16];
#pragma unroll
    for (int j = 0; j < 16; ++j) {
        float v = acc[j] * inv;
        v = fmaxf(v, __shfl_xor(v, 4, 64));
        v = fmaxf(v, __shfl_xor(v, 8, 64));
        r[j] = v;
    }
    if (lane < 4) {                              // q==0, ql 0..3: dims 16*ql..16*ql+15
        float4* o4 = (float4*)(out + (size_t)wid * DIM + ql * 16);
        o4[0] = make_float4(r[0],  r[1],  r[2],  r[3]);
        o4[1] = make_float4(r[4],  r[5],  r[6],  r[7]);
        o4[2] = make_float4(r[8],  r[9],  r[10], r[11]);
        o4[3] = make_float4(r[12], r[13], r[14], r[15]);
    }
}

extern "C" void kernel_launch(void* const* d_in, const int* in_sizes, int n_in,
                              void* d_out, int out_size, void* d_ws, size_t ws_size,
                              hipStream_t stream)
{
    const float* h_v  = (const float*)d_in[0];
    const int*   src  = (const int*)d_in[1];
    const int*   dst  = (const int*)d_in[2];
    const float* W_fc = (const float*)d_in[3];
    const float* b_fc = (const float*)d_in[4];
    const float* W_pi = (const float*)d_in[5];
    float* out = (float*)d_out;

    int N = in_sizes[0] / DIM;
    int E = in_sizes[1];

    // workspace layout
    unsigned short* ft = (unsigned short*)d_ws;            // N*256*2 = 25.6 MB
    size_t ftB = (((size_t)N * FDIM * 2) + 255) & ~(size_t)255;
    char*  p    = (char*)d_ws + ftB;
    int*   cnt  = (int*)(p);                               // N
    int*   off  = (int*)(p + 256 * 1024);                  // N+1
    int*   cur  = (int*)(p + 512 * 1024);                  // N
    int*   bsum = (int*)(p + 768 * 1024);                  // ceil(N/256)
    int*   ssrc = (int*)(p + 1024 * 1024);                 // E

    int nb = (N + 255) / 256;
    fc_kernel<<<2048, 256, 0, stream>>>(h_v, W_fc, b_fc, ft, N);
    zero_kernel<<<256, 256, 0, stream>>>(cnt, N);
    hist_kernel<<<1024, 256, 0, stream>>>(dst, cnt, E);
    scanA_kernel<<<nb, 256, 0, stream>>>(cnt, off, bsum, N);
    scanB_kernel<<<1, 256, 0, stream>>>(bsum, nb);
    scanC_kernel<<<nb, 256, 0, stream>>>(off, cur, bsum, N, E);
    scatter_kernel<<<1024, 256, 0, stream>>>(src, dst, cur, ssrc, E);
    int blocks = (N * 64 + 255) / 256;   // one 64-lane wave per node
    agg_kernel<<<blocks, 256, 0, stream>>>(ft, off, ssrc, W_pi, out, N);
}